// Round 12
// baseline (155.844 us; speedup 1.0000x reference)
//
#include <hip/hip_runtime.h>
#include <hip/hip_bf16.h>
#include <cstdint>
#include <cstddef>

// CRF NLL forward. B=256, T=512, L=64.
// R25: revert MFMA to 16x16x32 (R24's 32x32x16 regressed: 4-deep chains,
// 32cyc/MFMA occupancy = latency, never pipelines) + DUAL-CHUNK per wave
// (T15): each wave runs chunks 2k,2k+1 of one batch, steps interleaved.
// Model (closed across R21/R24): per-MFMA pipe occupancy == dependent
// latency (16.9cyc @16x16, 32 @32x32); cross-wave overlap weak (R21/R22
// nulls); wall = VALU-busy + MFMA-latency serialized per wave. Chunk B's
// pack/mul VALU issues while chunk A's MFMAs are in flight -> stalls
// overlap within the wave.
// 1024 waves, 256 blocks. Loop carries BfrA+BfrB+Areg+y-state (~170 VGPR;
// P transient, tails peeled). LDS 40KB: strans 32KB region + fbuf 8KB;
// G-scatter in two wave-local phases reusing strans.

constexpr int Bc = 256, Tc = 512, Lc = 64;
#define LOG64F 4.1588830833596715f

typedef __attribute__((ext_vector_type(8))) short v8s;   // 8 bf16
typedef __attribute__((ext_vector_type(4))) float v4f;
typedef __attribute__((ext_vector_type(4))) unsigned int v4u;

__device__ __forceinline__ float lane_bcast(float v, int lane) {
    return __uint_as_float(__builtin_amdgcn_readlane(__float_as_uint(v), lane));
}
__device__ __forceinline__ int lane_bcast_i(int v, int lane) {
    return __builtin_amdgcn_readlane(v, lane);
}
// rounded bf16x2 pack: low16 = bf16(x), high16 = bf16(y). 3 VALU insts.
__device__ __forceinline__ unsigned pk2(float x, float y) {
    const unsigned ux = __float_as_uint(x) + 0x8000u;
    const unsigned uy = __float_as_uint(y) + 0x8000u;
    return __builtin_amdgcn_perm(uy, ux, 0x07060302u);
}
// truncating bf16x2 pack: 1 VALU inst. Used only in the hot chain pack.
__device__ __forceinline__ unsigned pk2t(float x, float y) {
    return __builtin_amdgcn_perm(__float_as_uint(y), __float_as_uint(x), 0x07060302u);
}
__device__ __forceinline__ v8s as_v8s(v4u u) {
    v8s r; __builtin_memcpy(&r, &u, 16); return r;
}
__device__ __forceinline__ unsigned short bf16b(float x) {
    return (unsigned short)((__float_as_uint(x) + 0x8000u) >> 16);
}

// ---------------- Pass 1 ----------------
template<int CH>
__global__ __launch_bounds__(256, 2) void crf_pass1(
    const float* __restrict__ y_true,
    const float* __restrict__ y_pred,
    const float* __restrict__ trans,
    unsigned short* __restrict__ wsm,
    float* __restrict__ wss)
{
    constexpr int S = Tc / CH;            // steps per chunk (64)
    const int tid = threadIdx.x, lane = tid & 63, wv = tid >> 6;
    const int w = blockIdx.x * 4 + wv;    // 0 .. Bc*CH/2 - 1
    const int batch = w >> 2;             // CH=8: 4 chunk-pairs per batch
    const int c0 = 2 * (w & 3), c1 = c0 + 1;
    const int q = lane >> 4, m16 = lane & 15;
    const int rsub = q, csub = m16;

    __shared__ alignas(16) unsigned char smem_raw[32768];  // strans(16KB), then 4x8KB G scatter
    float* strans = (float*)smem_raw;
    __shared__ alignas(16) float fbuf[4][2][4][Lc];        // 8 KB: [wave][chunkSel][row][state]

    {   // stage trans with all 256 threads
        const v4f* t4 = (const v4f*)trans;
        #pragma unroll
        for (int k = 0; k < 4; ++k) {
            v4f v = t4[k * 256 + tid];
            *(v4f*)&strans[(k * 256 + tid) * 4] = v;
        }
    }
    __syncthreads();

    // Stationary A operands: Areg[I][K] elem jj = exp(trans[sig][16I+m16]),
    // sig=(jj&3)+4q+16(jj>>2)+32K (verified mapping).
    v8s Areg[4][2];
    #pragma unroll
    for (int I = 0; I < 4; ++I) {
        #pragma unroll
        for (int K = 0; K < 2; ++K) {
            float e[8];
            #pragma unroll
            for (int jj = 0; jj < 8; ++jj) {
                const int sig = (jj & 3) + 4 * q + 16 * (jj >> 2) + 32 * K;
                e[jj] = __expf(strans[sig * Lc + 16 * I + m16]);
            }
            v4u u;
            u.x = pk2(e[0], e[1]); u.y = pk2(e[2], e[3]);
            u.z = pk2(e[4], e[5]); u.w = pk2(e[6], e[7]);
            Areg[I][K] = as_v8s(u);
        }
    }

    const float* yp = y_pred + (size_t)batch * Tc * Lc;
    const float* yt = y_true + (size_t)batch * Tc * Lc;
    const v4f* yp4 = (const v4f*)yp;
    const v4f* yt4 = (const v4f*)yt;

    const int r0A = c0 * S + 1, r0B = c1 * S + 1;
    float psA = 0.f, tsA = 0.f, cA = 0.f;
    float psB = 0.f, tsB = 0.f, cB = 0.f;
    int lblA, lblB;
    {
        const float bt = yt[c0 * S * Lc + lane];
        lblA = (int)__builtin_ctzll(__ballot(bt > 0.5f));
    }
    {
        const float bt = yt[c1 * S * Lc + lane];
        lblB = (int)__builtin_ctzll(__ballot(bt > 0.5f));
    }

    auto ld4 = [&](const v4f* p, int baseRow) -> v4f {
        int r = baseRow + rsub; r = (r < Tc - 1) ? r : (Tc - 1);
        return p[r * 16 + csub];
    };

    const v4f z4 = {0.f, 0.f, 0.f, 0.f};
    v4f cypA = ld4(yp4, r0A), nypA = ld4(yp4, r0A + 4);
    v4f cytA = ld4(yt4, r0A), nytA = ld4(yt4, r0A + 4);
    v4f cypB = ld4(yp4, r0B), nypB = ld4(yp4, r0B + 4);
    v4f cytB = ld4(yt4, r0B), nytB = ld4(yt4, r0B + 4);

    // prologue + postamble F-build (kappa-only)
    auto prolF = [&](const v4f& cyp, int csel, float& c) {
        const float k0 = lane_bcast(cyp.x, 0)  + LOG64F;
        const float k1 = lane_bcast(cyp.x, 16) + LOG64F;
        const float k2 = lane_bcast(cyp.x, 32) + LOG64F;
        const float k3 = lane_bcast(cyp.x, 48) + LOG64F;
        c += ((k0 + k1) + (k2 + k3));
        const float kk = (rsub & 1) ? ((rsub & 2) ? k3 : k1)
                                    : ((rsub & 2) ? k2 : k0);
        v4f f;
        f.x = __expf(cyp.x - kk); f.y = __expf(cyp.y - kk);
        f.z = __expf(cyp.z - kk); f.w = __expf(cyp.w - kk);
        *(v4f*)&fbuf[wv][csel][rsub][4 * csub] = f;
    };
    prolF(cypA, 0, cA);
    prolF(cypB, 1, cB);

    auto postF = [&](const v4f& nyp, int csel, float& c, int rb) {
        const float k0 = lane_bcast(nyp.x, 0)  + LOG64F;
        const float k1 = lane_bcast(nyp.x, 16) + LOG64F;
        const float k2 = lane_bcast(nyp.x, 32) + LOG64F;
        const float k3 = lane_bcast(nyp.x, 48) + LOG64F;
        c += ((k0 + k1) + k2);
        if (rb + 7 <= Tc - 1) c += k3;              // phantom row-512 guard
        const float kk = (rsub & 1) ? ((rsub & 2) ? k3 : k1)
                                    : ((rsub & 2) ? k2 : k0);
        v4f f;
        f.x = __expf(nyp.x - kk); f.y = __expf(nyp.y - kk);
        f.z = __expf(nyp.z - kk); f.w = __expf(nyp.w - kk);
        *(v4f*)&fbuf[wv][csel][rsub][4 * csub] = f;
    };

    // B = identity columns, Jg = Jl (0..3)
    v8s BfrA[2][4], BfrB[2][4];
    #pragma unroll
    for (int Kc = 0; Kc < 2; ++Kc) {
        #pragma unroll
        for (int Jl = 0; Jl < 4; ++Jl) {
            v8s bb;
            #pragma unroll
            for (int jj = 0; jj < 8; ++jj) {
                const bool one = (m16 == 4 * q + (jj & 3)) &&
                                 (Jl == (jj >> 2) + 2 * Kc);
                bb[jj] = one ? (short)0x3F80 : (short)0;
            }
            BfrA[Kc][Jl] = bb;
            BfrB[Kc][Jl] = bb;
        }
    }

    v4f PA[4][4], PB[4][4];
    #pragma unroll
    for (int I = 0; I < 4; ++I)
        #pragma unroll
        for (int Jl = 0; Jl < 4; ++Jl) { PA[I][Jl] = z4; PB[I][Jl] = z4; }

    auto mstep = [&](int s, int csel, v8s (&Bfr)[2][4], v4f (&P)[4][4]) {
        __builtin_amdgcn_s_setprio(1);
        #pragma unroll
        for (int I = 0; I < 4; ++I) {
            const v4f F = *(const v4f*)&fbuf[wv][csel][s][16 * I + 4 * q];
            #pragma unroll
            for (int Jl = 0; Jl < 4; ++Jl) {
                v4f a = __builtin_amdgcn_mfma_f32_16x16x32_bf16(Areg[I][0], Bfr[0][Jl], z4, 0, 0, 0);
                a = __builtin_amdgcn_mfma_f32_16x16x32_bf16(Areg[I][1], Bfr[1][Jl], a, 0, 0, 0);
                P[I][Jl] = a * F;
            }
        }
        __builtin_amdgcn_s_setprio(0);
        #pragma unroll
        for (int Kc = 0; Kc < 2; ++Kc) {
            #pragma unroll
            for (int Jl = 0; Jl < 4; ++Jl) {
                v4u u;
                u.x = pk2t(P[2 * Kc][Jl].x,     P[2 * Kc][Jl].y);
                u.y = pk2t(P[2 * Kc][Jl].z,     P[2 * Kc][Jl].w);
                u.z = pk2t(P[2 * Kc + 1][Jl].x, P[2 * Kc + 1][Jl].y);
                u.w = pk2t(P[2 * Kc + 1][Jl].z, P[2 * Kc + 1][Jl].w);
                Bfr[Kc][Jl] = as_v8s(u);
            }
        }
    };

    auto scores4 = [&](const v4f& cyp, const v4f& cyt, int& lbl_carry,
                       float& psum, float& tsum) {
        psum = fmaf(cyp.x, cyt.x, psum); psum = fmaf(cyp.y, cyt.y, psum);
        psum = fmaf(cyp.z, cyt.z, psum); psum = fmaf(cyp.w, cyt.w, psum);
        const float has = fmaxf(fmaxf(cyt.x, cyt.y), fmaxf(cyt.z, cyt.w));
        int lidx = 0;
        lidx = (cyt.y > 0.5f) ? 1 : lidx;
        lidx = (cyt.z > 0.5f) ? 2 : lidx;
        lidx = (cyt.w > 0.5f) ? 3 : lidx;
        const unsigned long long m = __ballot(has > 0.5f);
        const int ln0 = (int)__builtin_ctz((unsigned)(m & 0xFFFFull));
        const int ln1 = (int)__builtin_ctz((unsigned)((m >> 16) & 0xFFFFull));
        const int ln2 = (int)__builtin_ctz((unsigned)((m >> 32) & 0xFFFFull));
        const int ln3 = (int)__builtin_ctz((unsigned)(m >> 48));
        const int lbl0 = 4 * ln0 + lane_bcast_i(lidx, ln0);
        const int lbl1 = 4 * ln1 + lane_bcast_i(lidx, 16 + ln1);
        const int lbl2 = 4 * ln2 + lane_bcast_i(lidx, 32 + ln2);
        const int lbl3 = 4 * ln3 + lane_bcast_i(lidx, 48 + ln3);
        const int lpA = (rsub & 2) ? lbl1 : lbl_carry;
        const int lpB = (rsub & 2) ? lbl2 : lbl0;
        const int lp  = (rsub & 1) ? lpB : lpA;
        lbl_carry = lbl3;
        const v4f tr = *(const v4f*)&strans[lp * Lc + 4 * csub];
        tsum = fmaf(cyt.x, tr.x, tsum); tsum = fmaf(cyt.y, tr.y, tsum);
        tsum = fmaf(cyt.z, tr.z, tsum); tsum = fmaf(cyt.w, tr.w, tsum);
    };

    #pragma unroll 1
    for (int bi = 0; bi < S / 4 - 1; ++bi) {
        const int rbA = r0A + 4 * bi;
        const int rbB = r0B + 4 * bi;
        const v4f lypA = ld4(yp4, rbA + 8);
        const v4f lytA = ld4(yt4, rbA + 8);
        const v4f lypB = ld4(yp4, rbB + 8);
        const v4f lytB = ld4(yt4, rbB + 8);

        scores4(cypA, cytA, lblA, psA, tsA);
        scores4(cypB, cytB, lblB, psB, tsB);

        mstep(0, 0, BfrA, PA); mstep(0, 1, BfrB, PB);
        mstep(1, 0, BfrA, PA); mstep(1, 1, BfrB, PB);
        mstep(2, 0, BfrA, PA); mstep(2, 1, BfrB, PB);
        mstep(3, 0, BfrA, PA); mstep(3, 1, BfrB, PB);

        postF(nypA, 0, cA, rbA);
        postF(nypB, 1, cB, rbB);

        cypA = nypA; nypA = lypA; cytA = nytA; nytA = lytA;
        cypB = nypB; nypB = lypB; cytB = nytB; nytB = lytB;
    }

    // peeled last block. A (even chunk) is never the global tail.
    const bool tailB = (c1 == CH - 1);
    scores4(cypA, cytA, lblA, psA, tsA);
    if (!tailB) {
        scores4(cypB, cytB, lblB, psB, tsB);
    } else {
        // 3 real tail rows (509..511), rsub3 phantom
        float pd = cypB.x * cytB.x;
        pd = fmaf(cypB.y, cytB.y, pd); pd = fmaf(cypB.z, cytB.z, pd); pd = fmaf(cypB.w, cytB.w, pd);
        const float has = fmaxf(fmaxf(cytB.x, cytB.y), fmaxf(cytB.z, cytB.w));
        int lidx = 0;
        lidx = (cytB.y > 0.5f) ? 1 : lidx;
        lidx = (cytB.z > 0.5f) ? 2 : lidx;
        lidx = (cytB.w > 0.5f) ? 3 : lidx;
        const unsigned long long m = __ballot(has > 0.5f);
        const int ln0 = (int)__builtin_ctz((unsigned)(m & 0xFFFFull));
        const int ln1 = (int)__builtin_ctz((unsigned)((m >> 16) & 0xFFFFull));
        const int lbl0 = 4 * ln0 + lane_bcast_i(lidx, ln0);
        const int lbl1 = 4 * ln1 + lane_bcast_i(lidx, 16 + ln1);
        const int lpA_ = (rsub & 2) ? lbl1 : lblB;
        const int lp  = (rsub & 1) ? lbl0 : lpA_;
        const v4f tr = *(const v4f*)&strans[lp * Lc + 4 * csub];
        float td = cytB.x * tr.x;
        td = fmaf(cytB.y, tr.y, td); td = fmaf(cytB.z, tr.z, td); td = fmaf(cytB.w, tr.w, td);
        if (rsub < 3) { psB += pd; tsB += td; }
    }

    mstep(0, 0, BfrA, PA); mstep(0, 1, BfrB, PB);
    mstep(1, 0, BfrA, PA); mstep(1, 1, BfrB, PB);
    mstep(2, 0, BfrA, PA); mstep(2, 1, BfrB, PB);
    mstep(3, 0, BfrA, PA);
    if (!tailB) mstep(3, 1, BfrB, PB);

    // ---- G store in pass2 A-frag order, via LDS scatter (strans now dead) ----
    __syncthreads();   // all waves done reading strans (scores/tail)
    unsigned short* myblob = ((unsigned short*)smem_raw) + wv * 4096;

    auto scatter_out = [&](v4f (&P)[4][4], int chunk) {
        #pragma unroll
        for (int I = 0; I < 4; ++I) {
            #pragma unroll
            for (int Jl = 0; Jl < 4; ++Jl) {
                float v[4] = {P[I][Jl].x, P[I][Jl].y, P[I][Jl].z, P[I][Jl].w};
                #pragma unroll
                for (int r = 0; r < 4; ++r) {
                    const int row = 16 * (m16 >> 2) + 4 * q + r;
                    const int gidx = I * 1024 + (Jl >> 1) * 512 + row * 8
                                   + 4 * (Jl & 1) + (m16 & 3);
                    myblob[gidx] = bf16b(v[r]);
                }
            }
        }
        const unsigned short* src = myblob + lane * 64;
        unsigned short* dst = wsm + (size_t)(batch * CH + chunk) * 4096 + lane * 64;
        #pragma unroll
        for (int t = 0; t < 8; ++t)
            *(v4u*)(dst + t * 8) = *(const v4u*)(src + t * 8);
    };
    scatter_out(PA, c0);   // wave-local region; per-wave DS ordering makes
    scatter_out(PB, c1);   // the phase-B reuse safe

    {
        #pragma unroll
        for (int k = 1; k < 64; k <<= 1) psA += __shfl_xor(psA, k);
        #pragma unroll
        for (int k = 1; k < 64; k <<= 1) tsA += __shfl_xor(tsA, k);
        #pragma unroll
        for (int k = 1; k < 64; k <<= 1) psB += __shfl_xor(psB, k);
        #pragma unroll
        for (int k = 1; k < 64; k <<= 1) tsB += __shfl_xor(tsB, k);
        if (lane == 0) {
            float* sA = wss + (batch * CH + c0) * 4;
            sA[0] = cA; sA[1] = psA; sA[2] = tsA;
            float* sB = wss + (batch * CH + c1) * 4;
            sB[0] = cB; sB[1] = psB; sB[2] = tsB;
        }
    }
}

// ---------------- Pass 2 ----------------
template<int CH>
__global__ __launch_bounds__(64, 1) void crf_pass2(
    const float* __restrict__ y_true,
    const float* __restrict__ y_pred,
    const unsigned short* __restrict__ wsm,
    const float* __restrict__ wss,
    float* __restrict__ out)
{
    const int lane = threadIdx.x;
    const int b = blockIdx.x;
    const int q = lane >> 4;

    __shared__ float arow[Lc];

    const float* yp = y_pred + (size_t)b * Tc * Lc;
    const float yp0 = yp[lane];
    float psum = yp0 * (((const float*)(y_true + (size_t)b * Tc * Lc))[lane]);
    float tsum = 0.0f;
    float c = lane_bcast(yp0, 0);
    arow[lane] = __expf(yp0 - c);

    v8s Bfr[2];
    #pragma unroll
    for (int cc = 0; cc < 2; ++cc) {
        const v4f lo = *(const v4f*)&arow[32 * cc + 4 * q];
        const v4f hi = *(const v4f*)&arow[32 * cc + 16 + 4 * q];
        v4u u;
        u.x = pk2(lo.x, lo.y); u.y = pk2(lo.z, lo.w);
        u.z = pk2(hi.x, hi.y); u.w = pk2(hi.z, hi.w);
        Bfr[cc] = as_v8s(u);
    }

    const v4f z4 = {0.f, 0.f, 0.f, 0.f};
    v4f P0 = z4, P1 = z4, P2 = z4, P3 = z4;

    v4u Abuf[2][8];
    {
        const v4u* g0 = (const v4u*)(wsm + (size_t)(b * CH) * 4096);
        #pragma unroll
        for (int s = 0; s < 8; ++s) Abuf[0][s] = g0[s * 64 + lane];
    }

    #pragma unroll
    for (int kk = 0; kk < CH; ++kk) {
        const int cur = kk & 1, nxt = cur ^ 1;
        if (kk < CH - 1) {
            const v4u* g1 = (const v4u*)(wsm + (size_t)(b * CH + kk + 1) * 4096);
            #pragma unroll
            for (int s = 0; s < 8; ++s) Abuf[nxt][s] = g1[s * 64 + lane];
        }
        v4f a0 = __builtin_amdgcn_mfma_f32_16x16x32_bf16(as_v8s(Abuf[cur][0]), Bfr[0], z4, 0, 0, 0);
        v4f a1 = __builtin_amdgcn_mfma_f32_16x16x32_bf16(as_v8s(Abuf[cur][2]), Bfr[0], z4, 0, 0, 0);
        v4f a2 = __builtin_amdgcn_mfma_f32_16x16x32_bf16(as_v8s(Abuf[cur][4]), Bfr[0], z4, 0, 0, 0);
        v4f a3 = __builtin_amdgcn_mfma_f32_16x16x32_bf16(as_v8s(Abuf[cur][6]), Bfr[0], z4, 0, 0, 0);
        a0 = __builtin_amdgcn_mfma_f32_16x16x32_bf16(as_v8s(Abuf[cur][1]), Bfr[1], a0, 0, 0, 0);
        a1 = __builtin_amdgcn_mfma_f32_16x16x32_bf16(as_v8s(Abuf[cur][3]), Bfr[1], a1, 0, 0, 0);
        a2 = __builtin_amdgcn_mfma_f32_16x16x32_bf16(as_v8s(Abuf[cur][5]), Bfr[1], a2, 0, 0, 0);
        a3 = __builtin_amdgcn_mfma_f32_16x16x32_bf16(as_v8s(Abuf[cur][7]), Bfr[1], a3, 0, 0, 0);

        const float sc = lane_bcast(a0.x, 0);
        const float inv = 1.0f / sc;
        c += __logf(sc);
        P0 = a0 * inv; P1 = a1 * inv; P2 = a2 * inv; P3 = a3 * inv;
        {
            v4u u;
            u.x = pk2(P0.x, P0.y); u.y = pk2(P0.z, P0.w);
            u.z = pk2(P1.x, P1.y); u.w = pk2(P1.z, P1.w);
            Bfr[0] = as_v8s(u);
        }
        {
            v4u u;
            u.x = pk2(P2.x, P2.y); u.y = pk2(P2.z, P2.w);
            u.z = pk2(P3.x, P3.y); u.w = pk2(P3.z, P3.w);
            Bfr[1] = as_v8s(u);
        }
    }

    float ftot = (((P0.x + P0.y) + (P0.z + P0.w)) + ((P1.x + P1.y) + (P1.z + P1.w)))
               + (((P2.x + P2.y) + (P2.z + P2.w)) + ((P3.x + P3.y) + (P3.z + P3.w)));
    ftot += __shfl_xor(ftot, 16);
    ftot += __shfl_xor(ftot, 32);

    #pragma unroll
    for (int k = 1; k < 64; k <<= 1) psum += __shfl_xor(psum, k);

    if (lane == 0) {
        float cs = c, ps = psum, ts = tsum;
        #pragma unroll
        for (int kk = 0; kk < CH; ++kk) {
            const float* s = wss + (b * CH + kk) * 4;
            cs += s[0]; ps += s[1]; ts += s[2];
        }
        out[b] = -(ps + ts - (cs + __logf(ftot)));
    }
}

extern "C" void kernel_launch(void* const* d_in, const int* in_sizes, int n_in,
                              void* d_out, int out_size, void* d_ws, size_t ws_size,
                              hipStream_t stream) {
    const float* y_true = (const float*)d_in[0];
    const float* y_pred = (const float*)d_in[1];
    const float* trans  = (const float*)d_in[2];
    float* outp = (float*)d_out;
    unsigned short* wsm = (unsigned short*)d_ws;

    // CH=8: G needs 256*8*8KB = 16MB + scalars at +16MB (32KB).
    // Dual-chunk: one wave per chunk-PAIR -> 1024 waves, 256 blocks.
    float* wss = (float*)((char*)d_ws + (16ull << 20));
    crf_pass1<8><<<dim3(256), dim3(256), 0, stream>>>(y_true, y_pred, trans, wsm, wss);
    crf_pass2<8><<<dim3(256), dim3(64),  0, stream>>>(y_true, y_pred, wsm, wss, outp);
}

// Round 13
// 144.842 us; speedup vs baseline: 1.0760x; 1.0760x over previous
//
#include <hip/hip_runtime.h>
#include <hip/hip_bf16.h>
#include <cstdint>
#include <cstddef>

// CRF NLL forward. B=256, T=512, L=64.
// R26 = revert to R22, the best-measured configuration (144.85us wall,
// pass1 71.4us): CH=8 h-split, s_setprio around MFMA cluster, truncating
// perm pack in the chain, one-time s_sleep phase stagger.
// Session ledger: pass1 floor is 71us across occupancy 2/4/8 waves-SIMD
// (R21), stagger (R22), merged-h ILP (R23), 32x32 MFMA (R24, -12%),
// dual-chunk pairing (R25, -14%). Only work-removal (R17 trunc pack,
// -11us) and setprio (R20, -3us) paid. Remaining wall = ~65-73us fixed
// harness cost + serial bf16-repack recursion floor; breaking it needs
// instruction-level scheduling beyond HIP source.

constexpr int Bc = 256, Tc = 512, Lc = 64;
#define LOG64F 4.1588830833596715f

typedef __attribute__((ext_vector_type(8))) short v8s;   // 8 bf16
typedef __attribute__((ext_vector_type(4))) float v4f;
typedef __attribute__((ext_vector_type(4))) unsigned int v4u;

__device__ __forceinline__ float lane_bcast(float v, int lane) {
    return __uint_as_float(__builtin_amdgcn_readlane(__float_as_uint(v), lane));
}
__device__ __forceinline__ int lane_bcast_i(int v, int lane) {
    return __builtin_amdgcn_readlane(v, lane);
}
// rounded bf16x2 pack: low16 = bf16(x), high16 = bf16(y). 3 VALU insts.
__device__ __forceinline__ unsigned pk2(float x, float y) {
    const unsigned ux = __float_as_uint(x) + 0x8000u;
    const unsigned uy = __float_as_uint(y) + 0x8000u;
    return __builtin_amdgcn_perm(uy, ux, 0x07060302u);
}
// truncating bf16x2 pack: 1 VALU inst. Used only in the hot chain pack.
__device__ __forceinline__ unsigned pk2t(float x, float y) {
    return __builtin_amdgcn_perm(__float_as_uint(y), __float_as_uint(x), 0x07060302u);
}
__device__ __forceinline__ v8s as_v8s(v4u u) {
    v8s r; __builtin_memcpy(&r, &u, 16); return r;
}
__device__ __forceinline__ unsigned short bf16b(float x) {
    return (unsigned short)((__float_as_uint(x) + 0x8000u) >> 16);
}

// ---------------- Pass 1 ----------------
template<int CH>
__global__ __launch_bounds__(256, 4) void crf_pass1(
    const float* __restrict__ y_true,
    const float* __restrict__ y_pred,
    const float* __restrict__ trans,
    unsigned short* __restrict__ wsm,
    float* __restrict__ wss)
{
    constexpr int S = Tc / CH;            // steps per chunk
    const int tid = threadIdx.x, lane = tid & 63, wv = tid >> 6;
    const int w = blockIdx.x * 4 + wv;
    const int batch = w / (2 * CH);
    const int chunk = (w >> 1) % CH;
    const int h = w & 1;
    const int q = lane >> 4, m16 = lane & 15;
    const int rsub = q, csub = m16;

    __shared__ alignas(16) unsigned char smem_raw[16384];  // strans, then G scatter
    float* strans = (float*)smem_raw;
    __shared__ alignas(16) float fbuf[4][4][Lc];           // 4 KB, single-buffered

    {   // stage trans with all 256 threads
        const v4f* t4 = (const v4f*)trans;
        #pragma unroll
        for (int k = 0; k < 4; ++k) {
            v4f v = t4[k * 256 + tid];
            *(v4f*)&strans[(k * 256 + tid) * 4] = v;
        }
    }
    __syncthreads();

    // Stationary A operands: Areg[I][K] elem jj = exp(trans[sig][16I+m16]),
    // sig=(jj&3)+4q+16(jj>>2)+32K (verified mapping).
    v8s Areg[4][2];
    #pragma unroll
    for (int I = 0; I < 4; ++I) {
        #pragma unroll
        for (int K = 0; K < 2; ++K) {
            float e[8];
            #pragma unroll
            for (int jj = 0; jj < 8; ++jj) {
                const int sig = (jj & 3) + 4 * q + 16 * (jj >> 2) + 32 * K;
                e[jj] = __expf(strans[sig * Lc + 16 * I + m16]);
            }
            v4u u;
            u.x = pk2(e[0], e[1]); u.y = pk2(e[2], e[3]);
            u.z = pk2(e[4], e[5]); u.w = pk2(e[6], e[7]);
            Areg[I][K] = as_v8s(u);
        }
    }

    const float* yp = y_pred + (size_t)batch * Tc * Lc;
    const float* yt = y_true + (size_t)batch * Tc * Lc;
    const v4f* yp4 = (const v4f*)yp;
    const v4f* yt4 = (const v4f*)yt;

    const int base = chunk * S;           // boundary row
    const int r0 = base + 1;
    float psum = 0.0f, tsum = 0.0f, c = 0.0f;
    int lbl_carry = 0;
    if (h == 0) {
        const float bt = yt[base * Lc + lane];
        lbl_carry = (int)__builtin_ctzll(__ballot(bt > 0.5f));
    }

    auto ld4 = [&](const v4f* p, int baseRow) -> v4f {
        int r = baseRow + rsub; r = (r < Tc - 1) ? r : (Tc - 1);
        return p[r * 16 + csub];
    };

    const v4f z4 = {0.f, 0.f, 0.f, 0.f};
    v4f cyp = ld4(yp4, r0), nyp = ld4(yp4, r0 + 4);
    v4f cyt = z4, nyt = z4;
    if (h == 0) { cyt = ld4(yt4, r0); nyt = ld4(yt4, r0 + 4); }

    {   // prologue F rows r0..r0+3 (kappa-only; all real rows for every chunk)
        const float k0 = lane_bcast(cyp.x, 0)  + LOG64F;
        const float k1 = lane_bcast(cyp.x, 16) + LOG64F;
        const float k2 = lane_bcast(cyp.x, 32) + LOG64F;
        const float k3 = lane_bcast(cyp.x, 48) + LOG64F;
        c += ((k0 + k1) + (k2 + k3));
        const float kk = (rsub & 1) ? ((rsub & 2) ? k3 : k1)
                                    : ((rsub & 2) ? k2 : k0);
        v4f f;
        f.x = __expf(cyp.x - kk); f.y = __expf(cyp.y - kk);
        f.z = __expf(cyp.z - kk); f.w = __expf(cyp.w - kk);
        *(v4f*)&fbuf[wv][rsub][4 * csub] = f;
    }

    // B = identity columns Jg = 2h + Jl
    v8s Bfr[2][2];
    #pragma unroll
    for (int Kc = 0; Kc < 2; ++Kc) {
        #pragma unroll
        for (int Jl = 0; Jl < 2; ++Jl) {
            v8s bb;
            #pragma unroll
            for (int jj = 0; jj < 8; ++jj) {
                const bool one = (m16 == 4 * q + (jj & 3)) &&
                                 (2 * h + Jl == (jj >> 2) + 2 * Kc);
                bb[jj] = one ? (short)0x3F80 : (short)0;
            }
            Bfr[Kc][Jl] = bb;
        }
    }

    v4f P[4][2];
    #pragma unroll
    for (int I = 0; I < 4; ++I) { P[I][0] = z4; P[I][1] = z4; }

    {   // phase-stagger: decorrelate wave step-phases on each SIMD.
        const int sid = ((blockIdx.x & 3) << 2) | wv;
        for (int i = 0; i < sid; ++i) __builtin_amdgcn_s_sleep(1);
    }

    auto mstep = [&](int s) {
        __builtin_amdgcn_s_setprio(1);
        #pragma unroll
        for (int I = 0; I < 4; ++I) {
            const v4f F = *(const v4f*)&fbuf[wv][s][16 * I + 4 * q];
            #pragma unroll
            for (int Jl = 0; Jl < 2; ++Jl) {
                v4f a = __builtin_amdgcn_mfma_f32_16x16x32_bf16(Areg[I][0], Bfr[0][Jl], z4, 0, 0, 0);
                a = __builtin_amdgcn_mfma_f32_16x16x32_bf16(Areg[I][1], Bfr[1][Jl], a, 0, 0, 0);
                P[I][Jl] = a * F;
            }
        }
        __builtin_amdgcn_s_setprio(0);
        #pragma unroll
        for (int Kc = 0; Kc < 2; ++Kc) {
            #pragma unroll
            for (int Jl = 0; Jl < 2; ++Jl) {
                v4u u;
                u.x = pk2t(P[2 * Kc][Jl].x,     P[2 * Kc][Jl].y);
                u.y = pk2t(P[2 * Kc][Jl].z,     P[2 * Kc][Jl].w);
                u.z = pk2t(P[2 * Kc + 1][Jl].x, P[2 * Kc + 1][Jl].y);
                u.w = pk2t(P[2 * Kc + 1][Jl].z, P[2 * Kc + 1][Jl].w);
                Bfr[Kc][Jl] = as_v8s(u);
            }
        }
    };

    auto scores4 = [&]() {
        psum = fmaf(cyp.x, cyt.x, psum); psum = fmaf(cyp.y, cyt.y, psum);
        psum = fmaf(cyp.z, cyt.z, psum); psum = fmaf(cyp.w, cyt.w, psum);
        const float has = fmaxf(fmaxf(cyt.x, cyt.y), fmaxf(cyt.z, cyt.w));
        int lidx = 0;
        lidx = (cyt.y > 0.5f) ? 1 : lidx;
        lidx = (cyt.z > 0.5f) ? 2 : lidx;
        lidx = (cyt.w > 0.5f) ? 3 : lidx;
        const unsigned long long m = __ballot(has > 0.5f);
        const int ln0 = (int)__builtin_ctz((unsigned)(m & 0xFFFFull));
        const int ln1 = (int)__builtin_ctz((unsigned)((m >> 16) & 0xFFFFull));
        const int ln2 = (int)__builtin_ctz((unsigned)((m >> 32) & 0xFFFFull));
        const int ln3 = (int)__builtin_ctz((unsigned)(m >> 48));
        const int lbl0 = 4 * ln0 + lane_bcast_i(lidx, ln0);
        const int lbl1 = 4 * ln1 + lane_bcast_i(lidx, 16 + ln1);
        const int lbl2 = 4 * ln2 + lane_bcast_i(lidx, 32 + ln2);
        const int lbl3 = 4 * ln3 + lane_bcast_i(lidx, 48 + ln3);
        const int lpA = (rsub & 2) ? lbl1 : lbl_carry;
        const int lpB = (rsub & 2) ? lbl2 : lbl0;
        const int lp  = (rsub & 1) ? lpB : lpA;
        lbl_carry = lbl3;
        const v4f tr = *(const v4f*)&strans[lp * Lc + 4 * csub];
        tsum = fmaf(cyt.x, tr.x, tsum); tsum = fmaf(cyt.y, tr.y, tsum);
        tsum = fmaf(cyt.z, tr.z, tsum); tsum = fmaf(cyt.w, tr.w, tsum);
    };

    #pragma unroll 1
    for (int bi = 0; bi < S / 4 - 1; ++bi) {
        const int rb = r0 + 4 * bi;
        const v4f lyp = ld4(yp4, rb + 8);
        v4f lyt = z4;
        if (h == 0) lyt = ld4(yt4, rb + 8);

        if (h == 0) scores4();
        mstep(0); mstep(1); mstep(2); mstep(3);

        {   // postamble: kappa-only F build for rows rb+4..rb+7
            const float k0 = lane_bcast(nyp.x, 0)  + LOG64F;
            const float k1 = lane_bcast(nyp.x, 16) + LOG64F;
            const float k2 = lane_bcast(nyp.x, 32) + LOG64F;
            const float k3 = lane_bcast(nyp.x, 48) + LOG64F;
            c += ((k0 + k1) + k2);
            if (rb + 7 <= Tc - 1) c += k3;          // phantom row-512 guard
            const float kk = (rsub & 1) ? ((rsub & 2) ? k3 : k1)
                                        : ((rsub & 2) ? k2 : k0);
            v4f f;
            f.x = __expf(nyp.x - kk); f.y = __expf(nyp.y - kk);
            f.z = __expf(nyp.z - kk); f.w = __expf(nyp.w - kk);
            *(v4f*)&fbuf[wv][rsub][4 * csub] = f;
        }
        cyp = nyp; nyp = lyp;
        if (h == 0) { cyt = nyt; nyt = lyt; }
    }

    if (chunk < CH - 1) {
        if (h == 0) scores4();
        mstep(0); mstep(1); mstep(2); mstep(3);
    } else {
        if (h == 0) {   // 3 real tail rows (509..511), rsub3 phantom
            float pd = cyp.x * cyt.x;
            pd = fmaf(cyp.y, cyt.y, pd); pd = fmaf(cyp.z, cyt.z, pd); pd = fmaf(cyp.w, cyt.w, pd);
            const float has = fmaxf(fmaxf(cyt.x, cyt.y), fmaxf(cyt.z, cyt.w));
            int lidx = 0;
            lidx = (cyt.y > 0.5f) ? 1 : lidx;
            lidx = (cyt.z > 0.5f) ? 2 : lidx;
            lidx = (cyt.w > 0.5f) ? 3 : lidx;
            const unsigned long long m = __ballot(has > 0.5f);
            const int ln0 = (int)__builtin_ctz((unsigned)(m & 0xFFFFull));
            const int ln1 = (int)__builtin_ctz((unsigned)((m >> 16) & 0xFFFFull));
            const int lbl0 = 4 * ln0 + lane_bcast_i(lidx, ln0);
            const int lbl1 = 4 * ln1 + lane_bcast_i(lidx, 16 + ln1);
            const int lpA = (rsub & 2) ? lbl1 : lbl_carry;
            const int lp  = (rsub & 1) ? lbl0 : lpA;
            const v4f tr = *(const v4f*)&strans[lp * Lc + 4 * csub];
            float td = cyt.x * tr.x;
            td = fmaf(cyt.y, tr.y, td); td = fmaf(cyt.z, tr.z, td); td = fmaf(cyt.w, tr.w, td);
            if (rsub < 3) { psum += pd; tsum += td; }
        }
        mstep(0); mstep(1); mstep(2);
    }

    // ---- G store in pass2 A-frag order, via LDS scatter (strans now dead) ----
    __syncthreads();   // all waves done reading strans
    unsigned short* myblob = ((unsigned short*)smem_raw) + wv * 2048;
    #pragma unroll
    for (int I = 0; I < 4; ++I) {
        #pragma unroll
        for (int Jl = 0; Jl < 2; ++Jl) {
            float v[4] = {P[I][Jl].x, P[I][Jl].y, P[I][Jl].z, P[I][Jl].w};
            #pragma unroll
            for (int r = 0; r < 4; ++r) {
                const int li = I * 512 + (16 * (m16 >> 2) + 4 * q + r) * 8
                             + 4 * Jl + (m16 & 3);
                myblob[li] = bf16b(v[r]);
            }
        }
    }
    {   // coalesced copy-out: this wave's 4 KB
        const int I = lane >> 4;
        const unsigned short* src = myblob + lane * 32;
        unsigned short* dst = wsm + (size_t)(batch * CH + chunk) * 4096
                            + I * 1024 + h * 512 + (lane & 15) * 32;
        #pragma unroll
        for (int t = 0; t < 4; ++t)
            *(v4u*)(dst + t * 8) = *(const v4u*)(src + t * 8);
    }

    if (h == 0) {
        #pragma unroll
        for (int k = 1; k < 64; k <<= 1) psum += __shfl_xor(psum, k);
        #pragma unroll
        for (int k = 1; k < 64; k <<= 1) tsum += __shfl_xor(tsum, k);
        if (lane == 0) {
            float* s = wss + (batch * CH + chunk) * 4;
            s[0] = c; s[1] = psum; s[2] = tsum;
        }
    }
}

// ---------------- Pass 2 ----------------
template<int CH>
__global__ __launch_bounds__(64, 1) void crf_pass2(
    const float* __restrict__ y_true,
    const float* __restrict__ y_pred,
    const unsigned short* __restrict__ wsm,
    const float* __restrict__ wss,
    float* __restrict__ out)
{
    const int lane = threadIdx.x;
    const int b = blockIdx.x;
    const int q = lane >> 4;

    __shared__ float arow[Lc];

    const float* yp = y_pred + (size_t)b * Tc * Lc;
    const float yp0 = yp[lane];
    float psum = yp0 * (((const float*)(y_true + (size_t)b * Tc * Lc))[lane]);
    float tsum = 0.0f;
    float c = lane_bcast(yp0, 0);
    arow[lane] = __expf(yp0 - c);

    v8s Bfr[2];
    #pragma unroll
    for (int cc = 0; cc < 2; ++cc) {
        const v4f lo = *(const v4f*)&arow[32 * cc + 4 * q];
        const v4f hi = *(const v4f*)&arow[32 * cc + 16 + 4 * q];
        v4u u;
        u.x = pk2(lo.x, lo.y); u.y = pk2(lo.z, lo.w);
        u.z = pk2(hi.x, hi.y); u.w = pk2(hi.z, hi.w);
        Bfr[cc] = as_v8s(u);
    }

    const v4f z4 = {0.f, 0.f, 0.f, 0.f};
    v4f P0 = z4, P1 = z4, P2 = z4, P3 = z4;

    v4u Abuf[2][8];
    {
        const v4u* g0 = (const v4u*)(wsm + (size_t)(b * CH) * 4096);
        #pragma unroll
        for (int s = 0; s < 8; ++s) Abuf[0][s] = g0[s * 64 + lane];
    }

    #pragma unroll
    for (int kk = 0; kk < CH; ++kk) {
        const int cur = kk & 1, nxt = cur ^ 1;
        if (kk < CH - 1) {
            const v4u* g1 = (const v4u*)(wsm + (size_t)(b * CH + kk + 1) * 4096);
            #pragma unroll
            for (int s = 0; s < 8; ++s) Abuf[nxt][s] = g1[s * 64 + lane];
        }
        v4f a0 = __builtin_amdgcn_mfma_f32_16x16x32_bf16(as_v8s(Abuf[cur][0]), Bfr[0], z4, 0, 0, 0);
        v4f a1 = __builtin_amdgcn_mfma_f32_16x16x32_bf16(as_v8s(Abuf[cur][2]), Bfr[0], z4, 0, 0, 0);
        v4f a2 = __builtin_amdgcn_mfma_f32_16x16x32_bf16(as_v8s(Abuf[cur][4]), Bfr[0], z4, 0, 0, 0);
        v4f a3 = __builtin_amdgcn_mfma_f32_16x16x32_bf16(as_v8s(Abuf[cur][6]), Bfr[0], z4, 0, 0, 0);
        a0 = __builtin_amdgcn_mfma_f32_16x16x32_bf16(as_v8s(Abuf[cur][1]), Bfr[1], a0, 0, 0, 0);
        a1 = __builtin_amdgcn_mfma_f32_16x16x32_bf16(as_v8s(Abuf[cur][3]), Bfr[1], a1, 0, 0, 0);
        a2 = __builtin_amdgcn_mfma_f32_16x16x32_bf16(as_v8s(Abuf[cur][5]), Bfr[1], a2, 0, 0, 0);
        a3 = __builtin_amdgcn_mfma_f32_16x16x32_bf16(as_v8s(Abuf[cur][7]), Bfr[1], a3, 0, 0, 0);

        const float sc = lane_bcast(a0.x, 0);
        const float inv = 1.0f / sc;
        c += __logf(sc);
        P0 = a0 * inv; P1 = a1 * inv; P2 = a2 * inv; P3 = a3 * inv;
        {
            v4u u;
            u.x = pk2(P0.x, P0.y); u.y = pk2(P0.z, P0.w);
            u.z = pk2(P1.x, P1.y); u.w = pk2(P1.z, P1.w);
            Bfr[0] = as_v8s(u);
        }
        {
            v4u u;
            u.x = pk2(P2.x, P2.y); u.y = pk2(P2.z, P2.w);
            u.z = pk2(P3.x, P3.y); u.w = pk2(P3.z, P3.w);
            Bfr[1] = as_v8s(u);
        }
    }

    float ftot = (((P0.x + P0.y) + (P0.z + P0.w)) + ((P1.x + P1.y) + (P1.z + P1.w)))
               + (((P2.x + P2.y) + (P2.z + P2.w)) + ((P3.x + P3.y) + (P3.z + P3.w)));
    ftot += __shfl_xor(ftot, 16);
    ftot += __shfl_xor(ftot, 32);

    #pragma unroll
    for (int k = 1; k < 64; k <<= 1) psum += __shfl_xor(psum, k);

    if (lane == 0) {
        float cs = c, ps = psum, ts = tsum;
        #pragma unroll
        for (int kk = 0; kk < CH; ++kk) {
            const float* s = wss + (b * CH + kk) * 4;
            cs += s[0]; ps += s[1]; ts += s[2];
        }
        out[b] = -(ps + ts - (cs + __logf(ftot)));
    }
}

extern "C" void kernel_launch(void* const* d_in, const int* in_sizes, int n_in,
                              void* d_out, int out_size, void* d_ws, size_t ws_size,
                              hipStream_t stream) {
    const float* y_true = (const float*)d_in[0];
    const float* y_pred = (const float*)d_in[1];
    const float* trans  = (const float*)d_in[2];
    float* outp = (float*)d_out;
    unsigned short* wsm = (unsigned short*)d_ws;

    // CH=8: G needs 256*8*8KB = 16MB + scalars at +16MB (32KB).
    float* wss = (float*)((char*)d_ws + (16ull << 20));
    crf_pass1<8><<<dim3(1024), dim3(256), 0, stream>>>(y_true, y_pred, trans, wsm, wss);
    crf_pass2<8><<<dim3(256),  dim3(64),  0, stream>>>(y_true, y_pred, wsm, wss, outp);
}